// Round 5
// baseline (152.255 us; speedup 1.0000x reference)
//
#include <hip/hip_runtime.h>
#include <math.h>

#define BATCH  512
#define NROWS  256
#define NVECS  8
#define VSIZE  128
#define DIM    1024   // NVECS*VSIZE
#define NCOMBO 256

// ---------------------------------------------------------------------------
// Single streaming kernel: dots + inline norms + combo expansion.
// NO LDS, NO barriers — every wave is independent; stores are emitted inside
// the r-loop so the 134 MB write stream runs for the kernel's whole life
// (write-bound steady state ~21 us at 6.3 TB/s).
//
// Mapping: grid (64,32) x 256 threads. Block (x,y) covers b in [8x,8x+8),
// r in [8y,8y+8). Wave wv owns b-rows {8x+2wv, 8x+2wv+1} x all 8 r.
// Lane l = (n = l>>3, c = l&7) covers elements [n*128 + c*16, +16).
//   - Q rows -> 32 VGPRs (one global read, L2-hot across the 32 y-blocks).
//   - W rows read directly from global per r: 64-lane x 16B strided loads;
//     each row is re-read by 256 waves -> L2/L1-hot (~9 us aggregate L2
//     traffic, hidden under the store shadow).
//   - dot0, dot1, w-sumsq reduced in one 3-step xor butterfly over c.
//   - cs[0..7] broadcast to all lanes via __shfl(x, 8j) (v_readlane).
//   - expand: lane l writes combos 4l..4l+3 as one float4 (1 KB/wave).
// ---------------------------------------------------------------------------
__global__ __launch_bounds__(256) void fused_kernel(
    const float* __restrict__ q, const float* __restrict__ w,
    float* __restrict__ out) {
  const int t    = threadIdx.x;
  const int wv   = t >> 6, lane = t & 63;
  const int bs   = blockIdx.x * 8, rs = blockIdx.y * 8;
  const int n    = lane >> 3, c = lane & 7;
  const int koff = n * VSIZE + c * 16;
  const int b0   = bs + 2 * wv;

  // Q rows -> registers; inline sub-vector inverse norms via butterfly.
  float4 qa[4], qb[4];
  float qs0 = 0.f, qs1 = 0.f;
  {
    const float* Q0 = q + (size_t)b0 * DIM + koff;
    #pragma unroll
    for (int j = 0; j < 4; ++j) {
      qa[j] = *(const float4*)(Q0 + 4 * j);
      qb[j] = *(const float4*)(Q0 + DIM + 4 * j);
      qs0 = fmaf(qa[j].x, qa[j].x, qs0); qs0 = fmaf(qa[j].y, qa[j].y, qs0);
      qs0 = fmaf(qa[j].z, qa[j].z, qs0); qs0 = fmaf(qa[j].w, qa[j].w, qs0);
      qs1 = fmaf(qb[j].x, qb[j].x, qs1); qs1 = fmaf(qb[j].y, qb[j].y, qs1);
      qs1 = fmaf(qb[j].z, qb[j].z, qs1); qs1 = fmaf(qb[j].w, qb[j].w, qs1);
    }
  }
  #pragma unroll
  for (int m = 1; m <= 4; m <<= 1) {
    qs0 += __shfl_xor(qs0, m, 64);
    qs1 += __shfl_xor(qs1, m, 64);
  }
  const float iq0 = 1.0f / fmaxf(sqrtf(qs0), 1e-8f);
  const float iq1 = 1.0f / fmaxf(sqrtf(qs1), 1e-8f);

  const float* Wbase = w + (size_t)rs * DIM + koff;
  float* out0 = out + ((size_t)b0 * NROWS + rs) * NCOMBO + lane * 4;

  #pragma unroll 2
  for (int r = 0; r < 8; ++r) {
    // --- dots + w-norm for row rs+r ---
    const float* Wr = Wbase + r * DIM;
    float s0 = 0.f, s1 = 0.f, wss = 0.f;
    #pragma unroll
    for (int j = 0; j < 4; ++j) {
      float4 w4 = *(const float4*)(Wr + 4 * j);
      s0 = fmaf(qa[j].x, w4.x, s0); s0 = fmaf(qa[j].y, w4.y, s0);
      s0 = fmaf(qa[j].z, w4.z, s0); s0 = fmaf(qa[j].w, w4.w, s0);
      s1 = fmaf(qb[j].x, w4.x, s1); s1 = fmaf(qb[j].y, w4.y, s1);
      s1 = fmaf(qb[j].z, w4.z, s1); s1 = fmaf(qb[j].w, w4.w, s1);
      wss = fmaf(w4.x, w4.x, wss); wss = fmaf(w4.y, w4.y, wss);
      wss = fmaf(w4.z, w4.z, wss); wss = fmaf(w4.w, w4.w, wss);
    }
    #pragma unroll
    for (int m = 1; m <= 4; m <<= 1) {
      s0  += __shfl_xor(s0, m, 64);
      s1  += __shfl_xor(s1, m, 64);
      wss += __shfl_xor(wss, m, 64);
    }
    const float iw  = 1.0f / fmaxf(sqrtf(wss), 1e-8f);
    const float cs0 = fmaxf(s0 * iq0 * iw, 0.f);
    const float cs1 = fmaxf(s1 * iq1 * iw, 0.f);

    // broadcast cs[n] from lane 8n to all lanes (uniform index -> readlane)
    float v0[8], v1[8];
    #pragma unroll
    for (int j = 0; j < 8; ++j) {
      v0[j] = __shfl(cs0, j * 8, 64);
      v1[j] = __shfl(cs1, j * 8, 64);
    }

    // --- expand + store both pairs for this r ---
    #pragma unroll
    for (int pp = 0; pp < 2; ++pp) {
      const float* v = pp ? v1 : v0;
      float t2 = (lane & 1)  ? 1.f - v[2] : v[2];
      float t3 = (lane & 2)  ? 1.f - v[3] : v[3];
      float t4 = (lane & 4)  ? 1.f - v[4] : v[4];
      float t5 = (lane & 8)  ? 1.f - v[5] : v[5];
      float t6 = (lane & 16) ? 1.f - v[6] : v[6];
      float t7 = (lane & 32) ? 1.f - v[7] : v[7];
      float base = ((t2 * t3) * (t4 * t5)) * (t6 * t7);
      float c0 = v[0], c1 = v[1];
      float4 o;
      o.x = base * (c0 * c1);
      o.y = base * ((1.f - c0) * c1);
      o.z = base * (c0 * (1.f - c1));
      o.w = base * ((1.f - c0) * (1.f - c1));
      *(float4*)(out0 + ((size_t)pp * NROWS + r) * NCOMBO) = o;
    }
  }
}

// ---------------------------------------------------------------------------
extern "C" void kernel_launch(void* const* d_in, const int* in_sizes, int n_in,
                              void* d_out, int out_size, void* d_ws, size_t ws_size,
                              hipStream_t stream) {
  const float* query  = (const float*)d_in[0];   // [512][1024]
  const float* weight = (const float*)d_in[1];   // [256][1024]
  float* out = (float*)d_out;                    // [512][256][256]
  (void)d_ws; (void)ws_size;

  hipLaunchKernelGGL(fused_kernel, dim3(64, 32), dim3(256), 0, stream,
                     query, weight, out);
}

// Round 6
// 145.061 us; speedup vs baseline: 1.0496x; 1.0496x over previous
//
#include <hip/hip_runtime.h>
#include <math.h>

#define BATCH  512
#define NROWS  256
#define NVECS  8
#define VSIZE  128
#define DIM    1024   // NVECS*VSIZE
#define NCOMBO 256

// ---------------------------------------------------------------------------
// Single fused kernel, store-streaming variant.
// Tile = 8 b x 8 r = 64 pairs/block, 256 threads (4 waves), grid 64x32.
//
// - W tile: contiguous coalesced global float4 loads -> padded LDS
//   (8 segs x (128+4) per row). Strided b128 LDS reads are conflict-free;
//   doing this stride against GLOBAL memory (R5) caused 64-line address
//   divergence per instruction — that was R5's regression.
// - Q rows -> 32 VGPRs; q sub-norms via 3-step xor butterfly (inline).
// - Per r: 4 b128 LDS reads, 48 FMA (dot0,dot1,wss), one 3-var butterfly,
//   16 v_readlane broadcasts, expand, 2 x 1KB coalesced float4 stores.
//   Stores are spread across the whole r-loop -> write-bound steady state,
//   no second barrier, no CS round-trip.
// ---------------------------------------------------------------------------
__global__ __launch_bounds__(256) void fused_kernel(
    const float* __restrict__ q, const float* __restrict__ w,
    float* __restrict__ out) {
  __shared__ __align__(16) float Ws[8 * 1056];  // 33 KB: 8 rows, 8x(128+4)
  const int t    = threadIdx.x;
  const int wv   = t >> 6, lane = t & 63;
  const int bs   = blockIdx.x * 8, rs = blockIdx.y * 8;
  const int n    = lane >> 3, c = lane & 7;
  const int koff = n * VSIZE + c * 16;
  const int b0   = bs + 2 * wv;

  // stage W tile (8 x 1024 floats): consecutive threads -> consecutive 16B
  #pragma unroll
  for (int i = 0; i < 8; ++i) {
    int f = i * 256 + t;        // float4 index 0..2047
    int g = f << 2;             // element index
    int row = g >> 10, e = g & 1023;
    float4 v = *(const float4*)(w + (size_t)(rs + row) * DIM + e);
    *(float4*)(Ws + row * 1056 + (e >> 7) * 132 + (e & 127)) = v;
  }

  // Q rows -> registers; inline sub-vector inverse norms via butterfly.
  float4 qa[4], qb[4];
  float qs0 = 0.f, qs1 = 0.f;
  {
    const float* Q0 = q + (size_t)b0 * DIM + koff;
    #pragma unroll
    for (int j = 0; j < 4; ++j) {
      qa[j] = *(const float4*)(Q0 + 4 * j);
      qb[j] = *(const float4*)(Q0 + DIM + 4 * j);
      qs0 = fmaf(qa[j].x, qa[j].x, qs0); qs0 = fmaf(qa[j].y, qa[j].y, qs0);
      qs0 = fmaf(qa[j].z, qa[j].z, qs0); qs0 = fmaf(qa[j].w, qa[j].w, qs0);
      qs1 = fmaf(qb[j].x, qb[j].x, qs1); qs1 = fmaf(qb[j].y, qb[j].y, qs1);
      qs1 = fmaf(qb[j].z, qb[j].z, qs1); qs1 = fmaf(qb[j].w, qb[j].w, qs1);
    }
  }
  #pragma unroll
  for (int m = 1; m <= 4; m <<= 1) {
    qs0 += __shfl_xor(qs0, m, 64);
    qs1 += __shfl_xor(qs1, m, 64);
  }
  const float iq0 = 1.0f / fmaxf(sqrtf(qs0), 1e-8f);
  const float iq1 = 1.0f / fmaxf(sqrtf(qs1), 1e-8f);

  __syncthreads();

  const float* Wb = Ws + n * 132 + c * 16;
  float* out0 = out + ((size_t)b0 * NROWS + rs) * NCOMBO + lane * 4;

  #pragma unroll 2
  for (int r = 0; r < 8; ++r) {
    // --- dots + w-norm for row rs+r (W from LDS) ---
    const float* Wr = Wb + r * 1056;
    float s0 = 0.f, s1 = 0.f, wss = 0.f;
    #pragma unroll
    for (int j = 0; j < 4; ++j) {
      float4 w4 = *(const float4*)(Wr + 4 * j);
      s0 = fmaf(qa[j].x, w4.x, s0); s0 = fmaf(qa[j].y, w4.y, s0);
      s0 = fmaf(qa[j].z, w4.z, s0); s0 = fmaf(qa[j].w, w4.w, s0);
      s1 = fmaf(qb[j].x, w4.x, s1); s1 = fmaf(qb[j].y, w4.y, s1);
      s1 = fmaf(qb[j].z, w4.z, s1); s1 = fmaf(qb[j].w, w4.w, s1);
      wss = fmaf(w4.x, w4.x, wss); wss = fmaf(w4.y, w4.y, wss);
      wss = fmaf(w4.z, w4.z, wss); wss = fmaf(w4.w, w4.w, wss);
    }
    #pragma unroll
    for (int m = 1; m <= 4; m <<= 1) {
      s0  += __shfl_xor(s0, m, 64);
      s1  += __shfl_xor(s1, m, 64);
      wss += __shfl_xor(wss, m, 64);
    }
    const float iw  = 1.0f / fmaxf(sqrtf(wss), 1e-8f);
    const float cs0 = fmaxf(s0 * iq0 * iw, 0.f);
    const float cs1 = fmaxf(s1 * iq1 * iw, 0.f);

    // broadcast cs[n] from lane 8n to all lanes (uniform index -> readlane)
    float v0[8], v1[8];
    #pragma unroll
    for (int j = 0; j < 8; ++j) {
      v0[j] = __shfl(cs0, j * 8, 64);
      v1[j] = __shfl(cs1, j * 8, 64);
    }

    // --- expand + store both b-rows for this r (stores spread over loop) ---
    #pragma unroll
    for (int pp = 0; pp < 2; ++pp) {
      const float* v = pp ? v1 : v0;
      float t2 = (lane & 1)  ? 1.f - v[2] : v[2];
      float t3 = (lane & 2)  ? 1.f - v[3] : v[3];
      float t4 = (lane & 4)  ? 1.f - v[4] : v[4];
      float t5 = (lane & 8)  ? 1.f - v[5] : v[5];
      float t6 = (lane & 16) ? 1.f - v[6] : v[6];
      float t7 = (lane & 32) ? 1.f - v[7] : v[7];
      float base = ((t2 * t3) * (t4 * t5)) * (t6 * t7);
      float c0 = v[0], c1 = v[1];
      float4 o;
      o.x = base * (c0 * c1);
      o.y = base * ((1.f - c0) * c1);
      o.z = base * (c0 * (1.f - c1));
      o.w = base * ((1.f - c0) * (1.f - c1));
      *(float4*)(out0 + ((size_t)pp * NROWS + r) * NCOMBO) = o;
    }
  }
}

// ---------------------------------------------------------------------------
extern "C" void kernel_launch(void* const* d_in, const int* in_sizes, int n_in,
                              void* d_out, int out_size, void* d_ws, size_t ws_size,
                              hipStream_t stream) {
  const float* query  = (const float*)d_in[0];   // [512][1024]
  const float* weight = (const float*)d_in[1];   // [256][1024]
  float* out = (float*)d_out;                    // [512][256][256]
  (void)d_ws; (void)ws_size;

  hipLaunchKernelGGL(fused_kernel, dim3(64, 32), dim3(256), 0, stream,
                     query, weight, out);
}